// Round 2
// baseline (39719.788 us; speedup 1.0000x reference)
//
#include <hip/hip_runtime.h>
#include <hip/hip_bf16.h>

#define N_NODESC 50000
#define N_EDGESC 500000
#define DIM 128
#define NREL 200
#define MWORDS 1563   /* ceil(50000/32) */
#define RRELU 0.22916666666666666f
#define RCHUNK 8

__device__ __forceinline__ float sigm(float x) { return 1.f / (1.f + __expf(-x)); }
__device__ __forceinline__ float tanh_fast(float x) {
  x = fminf(fmaxf(x, -15.f), 15.f);
  float e2 = __expf(-2.f * x);
  return (1.f - e2) / (1.f + e2);
}

// ---------------------------------------------------------------- mask + deg
__global__ void k_mask_deg(const int* __restrict__ src, const int* __restrict__ dst,
                           const int* __restrict__ ety, unsigned* __restrict__ mask,
                           int* __restrict__ deg) {
  int e = blockIdx.x * blockDim.x + threadIdx.x;
  if (e >= N_EDGESC) return;
  int r = ety[e], s = src[e], d = dst[e];
  atomicOr(&mask[r * MWORDS + (s >> 5)], 1u << (s & 31));
  atomicOr(&mask[r * MWORDS + (d >> 5)], 1u << (d & 31));
  atomicAdd(&deg[d], 1);
}

// ---------------------------------------------------------------- transpose
__global__ void k_transpose(const float* __restrict__ in, float* __restrict__ out,
                            int R, int C) {
  int i = blockIdx.x * blockDim.x + threadIdx.x;
  if (i >= R * C) return;
  int r = i / C, c = i - r * C;
  out[c * R + r] = in[i];
}

// ---------------------------------------------------------------- rel reduce
__global__ void k_rel_reduce(const float* __restrict__ nf, const unsigned* __restrict__ mask,
                             float* __restrict__ rel_sum, int* __restrict__ cnt) {
  int rel = blockIdx.x / RCHUNK;
  int chunk = blockIdx.x - rel * RCHUNK;
  int j = threadIdx.x;  // 128 threads, one feature each
  const int wpc = (MWORDS + RCHUNK - 1) / RCHUNK;
  int w0 = chunk * wpc;
  int w1 = min(MWORDS, w0 + wpc);
  float acc = 0.f;
  int c = 0;
  for (int w = w0; w < w1; ++w) {
    unsigned word = mask[rel * MWORDS + w];
    c += __popc(word);
    while (word) {
      int b = __ffs(word) - 1;
      word &= word - 1;
      acc += nf[(size_t)(w * 32 + b) * DIM + j];
    }
  }
  unsafeAtomicAdd(&rel_sum[rel * DIM + j], acc);
  if (j == 0) atomicAdd(&cnt[rel], c);
}

__global__ void k_rel_div(const float* __restrict__ rel_sum, const int* __restrict__ cnt,
                          float* __restrict__ rel_emb) {
  int i = blockIdx.x * blockDim.x + threadIdx.x;
  if (i >= NREL * DIM) return;
  int r = i / DIM;
  int c = cnt[r];
  rel_emb[i] = (c > 0) ? rel_sum[i] / (float)c : 0.f;
}

// ---------------------------------------------------------------- edge msg + scatter
// msg = [re|hs|ef] @ W1t + b1 ; atomic scatter to node_acc[dst]
__launch_bounds__(256, 2)
__global__ void k_edge_msg(const float* __restrict__ nf, const float* __restrict__ ef,
                           const float* __restrict__ rel_emb,
                           const int* __restrict__ src, const int* __restrict__ dst,
                           const int* __restrict__ ety,
                           const float* __restrict__ Wt, const float* __restrict__ bias,
                           float* __restrict__ node_acc) {
  __shared__ float A_s[64 * 132];
  __shared__ float Bs[64 * 128];
  const int t = threadIdx.x;
  const int e0 = blockIdx.x * 64;
  const int og = t & 15, eg = t >> 4;  // 16 out-groups x 8 outs, 16 edge-groups x 4 edges
  float acc[4][8];
#pragma unroll
  for (int i = 0; i < 4; ++i)
#pragma unroll
    for (int j = 0; j < 8; ++j) acc[i][j] = 0.f;

  for (int comp = 0; comp < 3; ++comp) {
    __syncthreads();
    for (int idx = t; idx < 64 * 32; idx += 256) {
      int e = idx >> 5, c4 = idx & 31;
      int ge = e0 + e;
      float4 v = make_float4(0.f, 0.f, 0.f, 0.f);
      if (ge < N_EDGESC) {
        const float* rowp;
        if (comp == 0)      rowp = rel_emb + (size_t)ety[ge] * DIM;
        else if (comp == 1) rowp = nf + (size_t)src[ge] * DIM;
        else                rowp = ef + (size_t)ge * DIM;
        v = *(const float4*)(rowp + c4 * 4);
      }
      *(float4*)(A_s + e * 132 + c4 * 4) = v;
    }
    for (int kc = 0; kc < 2; ++kc) {
      __syncthreads();
      int K0 = comp * 128 + kc * 64;
      for (int idx = t; idx < 64 * 32; idx += 256) {
        int kk = idx >> 5, c4 = idx & 31;
        *(float4*)(Bs + kk * 128 + c4 * 4) =
            *(const float4*)(Wt + (size_t)(K0 + kk) * DIM + c4 * 4);
      }
      __syncthreads();
      const float* arow = A_s + (eg * 4) * 132 + kc * 64;
      for (int k4 = 0; k4 < 16; ++k4) {
        float4 a[4];
#pragma unroll
        for (int i = 0; i < 4; ++i) a[i] = *(const float4*)(arow + i * 132 + k4 * 4);
#pragma unroll
        for (int kk = 0; kk < 4; ++kk) {
          const float* brow = Bs + (k4 * 4 + kk) * 128 + og * 8;
          float4 b0 = *(const float4*)(brow);
          float4 b1v = *(const float4*)(brow + 4);
#pragma unroll
          for (int i = 0; i < 4; ++i) {
            float av = ((const float*)&a[i])[kk];
            acc[i][0] += av * b0.x;  acc[i][1] += av * b0.y;
            acc[i][2] += av * b0.z;  acc[i][3] += av * b0.w;
            acc[i][4] += av * b1v.x; acc[i][5] += av * b1v.y;
            acc[i][6] += av * b1v.z; acc[i][7] += av * b1v.w;
          }
        }
      }
    }
  }
  float bv[8];
#pragma unroll
  for (int j = 0; j < 8; ++j) bv[j] = bias[og * 8 + j];
#pragma unroll
  for (int i = 0; i < 4; ++i) {
    int ge = e0 + eg * 4 + i;
    if (ge < N_EDGESC) {
      float* base = node_acc + (size_t)dst[ge] * DIM + og * 8;
#pragma unroll
      for (int j = 0; j < 8; ++j) unsafeAtomicAdd(base + j, acc[i][j] + bv[j]);
    }
  }
}

// ---------------------------------------------------------------- edge_msg + GRU (layer 0 only)
// x = [re|hs|hd] @ W2t + b2 ; new_e = GRU(x, ef) written in place into ef
__launch_bounds__(256, 2)
__global__ void k_edge_gru(const float* __restrict__ nf, float* __restrict__ ef,
                           const float* __restrict__ rel_emb,
                           const int* __restrict__ src, const int* __restrict__ dst,
                           const int* __restrict__ ety,
                           const float* __restrict__ W2t, const float* __restrict__ b2,
                           const float* __restrict__ Wiht, const float* __restrict__ Whht,
                           const float* __restrict__ bih, const float* __restrict__ bhh) {
  __shared__ float A_s[32 * 132];   // re/hs/hd then h (=ef)
  __shared__ float X_s[32 * 132];   // edge_msg
  __shared__ float Bs[64 * 128];
  const int t = threadIdx.x;
  const int e0 = blockIdx.x * 32;   // exact: 500000 = 32 * 15625
  const int og = t & 31, eg = t >> 5;  // 32 out-groups x 4 outs, 8 edge-groups x 4 edges
  float acc[4][4];
#pragma unroll
  for (int i = 0; i < 4; ++i)
#pragma unroll
    for (int j = 0; j < 4; ++j) acc[i][j] = 0.f;

  // ---- phase 1: edge_msg ----
  for (int comp = 0; comp < 3; ++comp) {
    __syncthreads();
    for (int idx = t; idx < 32 * 32; idx += 256) {
      int e = idx >> 5, c4 = idx & 31;
      int ge = e0 + e;
      const float* rowp;
      if (comp == 0)      rowp = rel_emb + (size_t)ety[ge] * DIM;
      else if (comp == 1) rowp = nf + (size_t)src[ge] * DIM;
      else                rowp = nf + (size_t)dst[ge] * DIM;
      *(float4*)(A_s + e * 132 + c4 * 4) = *(const float4*)(rowp + c4 * 4);
    }
    for (int kc = 0; kc < 2; ++kc) {
      __syncthreads();
      int K0 = comp * 128 + kc * 64;
      for (int idx = t; idx < 64 * 32; idx += 256) {
        int kk = idx >> 5, c4 = idx & 31;
        *(float4*)(Bs + kk * 128 + c4 * 4) =
            *(const float4*)(W2t + (size_t)(K0 + kk) * DIM + c4 * 4);
      }
      __syncthreads();
      const float* arow = A_s + (eg * 4) * 132 + kc * 64;
      for (int k4 = 0; k4 < 16; ++k4) {
        float4 a[4];
#pragma unroll
        for (int i = 0; i < 4; ++i) a[i] = *(const float4*)(arow + i * 132 + k4 * 4);
#pragma unroll
        for (int kk = 0; kk < 4; ++kk) {
          const float4 b0 = *(const float4*)(Bs + (k4 * 4 + kk) * 128 + og * 4);
#pragma unroll
          for (int i = 0; i < 4; ++i) {
            float av = ((const float*)&a[i])[kk];
            acc[i][0] += av * b0.x; acc[i][1] += av * b0.y;
            acc[i][2] += av * b0.z; acc[i][3] += av * b0.w;
          }
        }
      }
    }
  }
  // write x = edge_msg + b2 into X_s
  __syncthreads();
  {
    float4 bv = *(const float4*)(b2 + og * 4);
#pragma unroll
    for (int i = 0; i < 4; ++i) {
      float4 x;
      x.x = acc[i][0] + bv.x; x.y = acc[i][1] + bv.y;
      x.z = acc[i][2] + bv.z; x.w = acc[i][3] + bv.w;
      *(float4*)(X_s + (eg * 4 + i) * 132 + og * 4) = x;
    }
  }
  // load h = ef into A_s
  for (int idx = t; idx < 32 * 32; idx += 256) {
    int e = idx >> 5, c4 = idx & 31;
    *(float4*)(A_s + e * 132 + c4 * 4) = *(const float4*)(ef + (size_t)(e0 + e) * DIM + c4 * 4);
  }

  // ---- phase 2: GRU gates r, z, n ----
  float r_g[4][4], z_g[4][4];
  for (int g = 0; g < 3; ++g) {
    float gi[4][4], gh[4][4];
#pragma unroll
    for (int i = 0; i < 4; ++i)
#pragma unroll
      for (int j = 0; j < 4; ++j) { gi[i][j] = 0.f; gh[i][j] = 0.f; }
#pragma unroll
    for (int ssel = 0; ssel < 2; ++ssel) {
      const float* Wsrc = ssel ? Whht : Wiht;            // [128][384]
      const float* Asrc = ssel ? (const float*)A_s : (const float*)X_s;
      for (int kc = 0; kc < 2; ++kc) {
        __syncthreads();
        for (int idx = t; idx < 64 * 32; idx += 256) {
          int kk = idx >> 5, c4 = idx & 31;
          *(float4*)(Bs + kk * 128 + c4 * 4) =
              *(const float4*)(Wsrc + (size_t)(kc * 64 + kk) * 384 + g * 128 + c4 * 4);
        }
        __syncthreads();
        const float* arow = Asrc + (eg * 4) * 132 + kc * 64;
        for (int k4 = 0; k4 < 16; ++k4) {
          float4 a[4];
#pragma unroll
          for (int i = 0; i < 4; ++i) a[i] = *(const float4*)(arow + i * 132 + k4 * 4);
#pragma unroll
          for (int kk = 0; kk < 4; ++kk) {
            const float4 b0 = *(const float4*)(Bs + (k4 * 4 + kk) * 128 + og * 4);
#pragma unroll
            for (int i = 0; i < 4; ++i) {
              float av = ((const float*)&a[i])[kk];
              if (ssel == 0) {
                gi[i][0] += av * b0.x; gi[i][1] += av * b0.y;
                gi[i][2] += av * b0.z; gi[i][3] += av * b0.w;
              } else {
                gh[i][0] += av * b0.x; gh[i][1] += av * b0.y;
                gh[i][2] += av * b0.z; gh[i][3] += av * b0.w;
              }
            }
          }
        }
      }
    }
    if (g < 2) {
      float4 bi = *(const float4*)(bih + g * 128 + og * 4);
      float4 bh = *(const float4*)(bhh + g * 128 + og * 4);
#pragma unroll
      for (int i = 0; i < 4; ++i)
#pragma unroll
        for (int j = 0; j < 4; ++j) {
          float s = gi[i][j] + gh[i][j] + ((const float*)&bi)[j] + ((const float*)&bh)[j];
          float v = sigm(s);
          if (g == 0) r_g[i][j] = v; else z_g[i][j] = v;
        }
    } else {
      float4 bi = *(const float4*)(bih + 256 + og * 4);
      float4 bh = *(const float4*)(bhh + 256 + og * 4);
#pragma unroll
      for (int i = 0; i < 4; ++i) {
        float4 res;
        float* rp = (float*)&res;
#pragma unroll
        for (int j = 0; j < 4; ++j) {
          float i_n = gi[i][j] + ((const float*)&bi)[j];
          float h_n = gh[i][j] + ((const float*)&bh)[j];
          float nv = tanh_fast(i_n + r_g[i][j] * h_n);
          float hv = A_s[(eg * 4 + i) * 132 + og * 4 + j];
          rp[j] = (1.f - z_g[i][j]) * nv + z_g[i][j] * hv;
        }
        *(float4*)(ef + (size_t)(e0 + eg * 4 + i) * DIM + og * 4) = res;
      }
    }
  }
}

// ---------------------------------------------------------------- node update
__launch_bounds__(256, 2)
__global__ void k_node(const float* __restrict__ nf, const float* __restrict__ node_acc,
                       const int* __restrict__ deg, const float* __restrict__ W3t,
                       const float* __restrict__ b3, float* __restrict__ out) {
  __shared__ float A_s[64 * 132];
  __shared__ float Bs[64 * 128];
  const int t = threadIdx.x;
  const int n0 = blockIdx.x * 64;
  const int og = t & 15, ng = t >> 4;
  float acc[4][8];
#pragma unroll
  for (int i = 0; i < 4; ++i)
#pragma unroll
    for (int j = 0; j < 8; ++j) acc[i][j] = 0.f;

  for (int idx = t; idx < 64 * 32; idx += 256) {
    int e = idx >> 5, c4 = idx & 31;
    int gn = n0 + e;
    float4 v = make_float4(0.f, 0.f, 0.f, 0.f);
    if (gn < N_NODESC) v = *(const float4*)(nf + (size_t)gn * DIM + c4 * 4);
    *(float4*)(A_s + e * 132 + c4 * 4) = v;
  }
  for (int kc = 0; kc < 2; ++kc) {
    __syncthreads();
    for (int idx = t; idx < 64 * 32; idx += 256) {
      int kk = idx >> 5, c4 = idx & 31;
      *(float4*)(Bs + kk * 128 + c4 * 4) =
          *(const float4*)(W3t + (size_t)(kc * 64 + kk) * DIM + c4 * 4);
    }
    __syncthreads();
    const float* arow = A_s + (ng * 4) * 132 + kc * 64;
    for (int k4 = 0; k4 < 16; ++k4) {
      float4 a[4];
#pragma unroll
      for (int i = 0; i < 4; ++i) a[i] = *(const float4*)(arow + i * 132 + k4 * 4);
#pragma unroll
      for (int kk = 0; kk < 4; ++kk) {
        const float* brow = Bs + (k4 * 4 + kk) * 128 + og * 8;
        float4 b0 = *(const float4*)(brow);
        float4 b1v = *(const float4*)(brow + 4);
#pragma unroll
        for (int i = 0; i < 4; ++i) {
          float av = ((const float*)&a[i])[kk];
          acc[i][0] += av * b0.x;  acc[i][1] += av * b0.y;
          acc[i][2] += av * b0.z;  acc[i][3] += av * b0.w;
          acc[i][4] += av * b1v.x; acc[i][5] += av * b1v.y;
          acc[i][6] += av * b1v.z; acc[i][7] += av * b1v.w;
        }
      }
    }
  }
  float bv[8];
#pragma unroll
  for (int j = 0; j < 8; ++j) bv[j] = b3[og * 8 + j];
#pragma unroll
  for (int i = 0; i < 4; ++i) {
    int gn = n0 + ng * 4 + i;
    if (gn < N_NODESC) {
      float inv = 1.f / (float)max(deg[gn], 1);
      const float* nap = node_acc + (size_t)gn * DIM + og * 8;
      float* op = out + (size_t)gn * DIM + og * 8;
#pragma unroll
      for (int j = 0; j < 8; ++j) {
        float pre = acc[i][j] + bv[j] + nap[j] * inv;
        op[j] = (pre >= 0.f) ? pre : RRELU * pre;
      }
    }
  }
}

// ---------------------------------------------------------------- launch
extern "C" void kernel_launch(void* const* d_in, const int* in_sizes, int n_in,
                              void* d_out, int out_size, void* d_ws, size_t ws_size,
                              hipStream_t stream) {
  const float* nf0 = (const float*)d_in[0];
  float* ef = (float*)d_in[1];
  const int* src = (const int*)d_in[2];
  const int* dst = (const int*)d_in[3];
  const int* ety = (const int*)d_in[4];
  const float* W1 = (const float*)d_in[6];
  const float* b1 = (const float*)d_in[7];
  const float* W2 = (const float*)d_in[8];
  const float* b2 = (const float*)d_in[9];
  const float* W3 = (const float*)d_in[10];
  const float* b3 = (const float*)d_in[11];
  const float* Wih = (const float*)d_in[12];
  const float* Whh = (const float*)d_in[13];
  const float* bih = (const float*)d_in[14];
  const float* bhh = (const float*)d_in[15];
  float* out = (float*)d_out;

  char* wsb = (char*)d_ws;
  size_t off = 0;
  auto alloc = [&](size_t b) {
    char* p = wsb + off;
    off = (off + b + 255) & ~(size_t)255;
    return p;
  };
  unsigned* mask  = (unsigned*)alloc(sizeof(unsigned) * NREL * MWORDS);
  int* deg        = (int*)alloc(sizeof(int) * N_NODESC);
  float* rel_sum  = (float*)alloc(sizeof(float) * NREL * DIM);
  int* cnt        = (int*)alloc(sizeof(int) * NREL);
  float* rel_emb  = (float*)alloc(sizeof(float) * NREL * DIM);
  float* node_acc = (float*)alloc(sizeof(float) * N_NODESC * DIM);
  float* W1t      = (float*)alloc(sizeof(float) * 2 * 384 * DIM);
  float* W2t      = (float*)alloc(sizeof(float) * 384 * DIM);
  float* W3t      = (float*)alloc(sizeof(float) * 2 * DIM * DIM);
  float* Wiht     = (float*)alloc(sizeof(float) * DIM * 384);
  float* Whht     = (float*)alloc(sizeof(float) * DIM * 384);

  hipMemsetAsync(mask, 0, sizeof(unsigned) * NREL * MWORDS, stream);
  hipMemsetAsync(deg, 0, sizeof(int) * N_NODESC, stream);
  k_mask_deg<<<(N_EDGESC + 255) / 256, 256, 0, stream>>>(src, dst, ety, mask, deg);

  // weight transposes (Wt[k][o] = W[o][k])
  k_transpose<<<192, 256, 0, stream>>>(W1, W1t, 128, 384);
  k_transpose<<<192, 256, 0, stream>>>(W1 + 128 * 384, W1t + 384 * 128, 128, 384);
  k_transpose<<<192, 256, 0, stream>>>(W2, W2t, 128, 384);
  k_transpose<<<64, 256, 0, stream>>>(W3, W3t, 128, 128);
  k_transpose<<<64, 256, 0, stream>>>(W3 + 128 * 128, W3t + 128 * 128, 128, 128);
  k_transpose<<<192, 256, 0, stream>>>(Wih, Wiht, 384, 128);
  k_transpose<<<192, 256, 0, stream>>>(Whh, Whht, 384, 128);

  for (int l = 0; l < 2; ++l) {
    const float* nfl = l ? (const float*)out : nf0;
    hipMemsetAsync(rel_sum, 0, sizeof(float) * NREL * DIM, stream);
    hipMemsetAsync(cnt, 0, sizeof(int) * NREL, stream);
    hipMemsetAsync(node_acc, 0, sizeof(float) * N_NODESC * DIM, stream);
    k_rel_reduce<<<NREL * RCHUNK, 128, 0, stream>>>(nfl, mask, rel_sum, cnt);
    k_rel_div<<<(NREL * DIM + 255) / 256, 256, 0, stream>>>(rel_sum, cnt, rel_emb);
    k_edge_msg<<<(N_EDGESC + 63) / 64, 256, 0, stream>>>(
        nfl, ef, rel_emb, src, dst, ety,
        W1t + (size_t)l * 384 * DIM, b1 + l * DIM, node_acc);
    if (l == 0) {
      k_edge_gru<<<N_EDGESC / 32, 256, 0, stream>>>(
          nfl, ef, rel_emb, src, dst, ety, W2t, b2, Wiht, Whht, bih, bhh);
    }
    k_node<<<(N_NODESC + 63) / 64, 256, 0, stream>>>(
        nfl, node_acc, deg, W3t + (size_t)l * DIM * DIM, b3 + l * DIM, out);
  }
}

// Round 3
// 7450.823 us; speedup vs baseline: 5.3309x; 5.3309x over previous
//
#include <hip/hip_runtime.h>
#include <hip/hip_bf16.h>

#define N_NODESC 50000
#define N_EDGESC 500000
#define DIM 128
#define NREL 200
#define MWORDS 1563   /* ceil(50000/32) */
#define RRELU 0.22916666666666666f
#define RCHUNK 8

__device__ __forceinline__ float sigm(float x) { return 1.f / (1.f + __expf(-x)); }
__device__ __forceinline__ float tanh_fast(float x) {
  x = fminf(fmaxf(x, -15.f), 15.f);
  float e2 = __expf(-2.f * x);
  return (1.f - e2) / (1.f + e2);
}

// ---------------------------------------------------------------- mask + deg
__global__ void k_mask_deg(const int* __restrict__ src, const int* __restrict__ dst,
                           const int* __restrict__ ety, unsigned* __restrict__ mask,
                           int* __restrict__ deg) {
  int e = blockIdx.x * blockDim.x + threadIdx.x;
  if (e >= N_EDGESC) return;
  int r = ety[e], s = src[e], d = dst[e];
  atomicOr(&mask[r * MWORDS + (s >> 5)], 1u << (s & 31));
  atomicOr(&mask[r * MWORDS + (d >> 5)], 1u << (d & 31));
  atomicAdd(&deg[d], 1);
}

// ---------------------------------------------------------------- transpose
__global__ void k_transpose(const float* __restrict__ in, float* __restrict__ out,
                            int R, int C) {
  int i = blockIdx.x * blockDim.x + threadIdx.x;
  if (i >= R * C) return;
  int r = i / C, c = i - r * C;
  out[c * R + r] = in[i];
}

// ---------------------------------------------------------------- rel reduce
__global__ void k_rel_reduce(const float* __restrict__ nf, const unsigned* __restrict__ mask,
                             float* __restrict__ rel_sum, int* __restrict__ cnt) {
  int rel = blockIdx.x / RCHUNK;
  int chunk = blockIdx.x - rel * RCHUNK;
  int j = threadIdx.x;  // 128 threads, one feature each
  const int wpc = (MWORDS + RCHUNK - 1) / RCHUNK;
  int w0 = chunk * wpc;
  int w1 = min(MWORDS, w0 + wpc);
  float acc = 0.f;
  int c = 0;
  for (int w = w0; w < w1; ++w) {
    unsigned word = mask[rel * MWORDS + w];
    c += __popc(word);
    while (word) {
      int b = __ffs(word) - 1;
      word &= word - 1;
      acc += nf[(size_t)(w * 32 + b) * DIM + j];
    }
  }
  unsafeAtomicAdd(&rel_sum[rel * DIM + j], acc);
  if (j == 0) atomicAdd(&cnt[rel], c);
}

__global__ void k_rel_div(const float* __restrict__ rel_sum, const int* __restrict__ cnt,
                          float* __restrict__ rel_emb) {
  int i = blockIdx.x * blockDim.x + threadIdx.x;
  if (i >= NREL * DIM) return;
  int r = i / DIM;
  int c = cnt[r];
  rel_emb[i] = (c > 0) ? rel_sum[i] / (float)c : 0.f;
}

// ---------------------------------------------------------------- edge msg + scatter
// msg = [re|hs|ef] @ W1t + b1 ; atomic scatter to node_acc[dst]
__launch_bounds__(256, 2)
__global__ void k_edge_msg(const float* __restrict__ nf, const float* __restrict__ ef,
                           const float* __restrict__ rel_emb,
                           const int* __restrict__ src, const int* __restrict__ dst,
                           const int* __restrict__ ety,
                           const float* __restrict__ Wt, const float* __restrict__ bias,
                           float* __restrict__ node_acc) {
  __shared__ float A_s[64 * 132];
  __shared__ float Bs[64 * 128];
  const int t = threadIdx.x;
  const int e0 = blockIdx.x * 64;
  const int og = t & 15, eg = t >> 4;  // 16 out-groups x 8 outs, 16 edge-groups x 4 edges
  float acc[4][8];
#pragma unroll
  for (int i = 0; i < 4; ++i)
#pragma unroll
    for (int j = 0; j < 8; ++j) acc[i][j] = 0.f;

  for (int comp = 0; comp < 3; ++comp) {
    __syncthreads();
    for (int idx = t; idx < 64 * 32; idx += 256) {
      int e = idx >> 5, c4 = idx & 31;
      int ge = e0 + e;
      float4 v = make_float4(0.f, 0.f, 0.f, 0.f);
      if (ge < N_EDGESC) {
        const float* rowp;
        if (comp == 0)      rowp = rel_emb + (size_t)ety[ge] * DIM;
        else if (comp == 1) rowp = nf + (size_t)src[ge] * DIM;
        else                rowp = ef + (size_t)ge * DIM;
        v = *(const float4*)(rowp + c4 * 4);
      }
      *(float4*)(A_s + e * 132 + c4 * 4) = v;
    }
    for (int kc = 0; kc < 2; ++kc) {
      __syncthreads();
      int K0 = comp * 128 + kc * 64;
      for (int idx = t; idx < 64 * 32; idx += 256) {
        int kk = idx >> 5, c4 = idx & 31;
        *(float4*)(Bs + kk * 128 + c4 * 4) =
            *(const float4*)(Wt + (size_t)(K0 + kk) * DIM + c4 * 4);
      }
      __syncthreads();
      const float* arow = A_s + (eg * 4) * 132 + kc * 64;
      for (int k4 = 0; k4 < 16; ++k4) {
        float4 a[4];
#pragma unroll
        for (int i = 0; i < 4; ++i) a[i] = *(const float4*)(arow + i * 132 + k4 * 4);
#pragma unroll
        for (int kk = 0; kk < 4; ++kk) {
          const float* brow = Bs + (k4 * 4 + kk) * 128 + og * 8;
          float4 b0 = *(const float4*)(brow);
          float4 b1v = *(const float4*)(brow + 4);
#pragma unroll
          for (int i = 0; i < 4; ++i) {
            float av = ((const float*)&a[i])[kk];
            acc[i][0] += av * b0.x;  acc[i][1] += av * b0.y;
            acc[i][2] += av * b0.z;  acc[i][3] += av * b0.w;
            acc[i][4] += av * b1v.x; acc[i][5] += av * b1v.y;
            acc[i][6] += av * b1v.z; acc[i][7] += av * b1v.w;
          }
        }
      }
    }
  }
  float bv[8];
#pragma unroll
  for (int j = 0; j < 8; ++j) bv[j] = bias[og * 8 + j];
#pragma unroll
  for (int i = 0; i < 4; ++i) {
    int ge = e0 + eg * 4 + i;
    if (ge < N_EDGESC) {
      float* base = node_acc + (size_t)dst[ge] * DIM + og * 8;
#pragma unroll
      for (int j = 0; j < 8; ++j) unsafeAtomicAdd(base + j, acc[i][j] + bv[j]);
    }
  }
}

// ---------------------------------------------------------------- GRU helpers
// 32-edge tile, 4 edges x 4 outs per thread, K processed in 32-wide chunks.
__device__ __forceinline__ void mac32(const float* __restrict__ Asrc, int kofs,
                                      const float* __restrict__ Bs,
                                      int eg, int og, float acc[4][4]) {
  const float* arow = Asrc + (eg * 4) * 132 + kofs;
#pragma unroll
  for (int k4 = 0; k4 < 8; ++k4) {
    float4 a[4];
#pragma unroll
    for (int i = 0; i < 4; ++i) a[i] = *(const float4*)(arow + i * 132 + k4 * 4);
#pragma unroll
    for (int kk = 0; kk < 4; ++kk) {
      const float4 b0 = *(const float4*)(Bs + (k4 * 4 + kk) * 128 + og * 4);
#pragma unroll
      for (int i = 0; i < 4; ++i) {
        float av = ((const float*)&a[i])[kk];
        acc[i][0] += av * b0.x; acc[i][1] += av * b0.y;
        acc[i][2] += av * b0.z; acc[i][3] += av * b0.w;
      }
    }
  }
}

__device__ __forceinline__ void stageB(float* __restrict__ Bs, const float* __restrict__ W,
                                       int row0, int rstride, int colofs, int t) {
  for (int idx = t; idx < 32 * 32; idx += 256) {
    int kk = idx >> 5, c4 = idx & 31;
    *(float4*)(Bs + kk * 128 + c4 * 4) =
        *(const float4*)(W + (size_t)(row0 + kk) * rstride + colofs + c4 * 4);
  }
}

// ---------------------------------------------------------------- edge_msg + GRU (layer 0)
// x = [re|hs|hd] @ W2t + b2 ; new_e = GRU(x, ef) written in place into ef.
// Gate order i_n -> r -> h_n(-> n) -> z keeps <=32 accumulators live (no spills);
// intermediates i_n / n live in LDS (N_s), per-thread-exclusive 4x4 cells.
__launch_bounds__(256, 2)
__global__ void k_edge_gru(const float* __restrict__ nf, float* __restrict__ ef,
                           const float* __restrict__ rel_emb,
                           const int* __restrict__ src, const int* __restrict__ dst,
                           const int* __restrict__ ety,
                           const float* __restrict__ W2t, const float* __restrict__ b2,
                           const float* __restrict__ Wiht, const float* __restrict__ Whht,
                           const float* __restrict__ bih, const float* __restrict__ bhh) {
  __shared__ float A_s[32 * 132];   // h (= ef rows)
  __shared__ float X_s[32 * 132];   // x (= edge_msg)
  __shared__ float N_s[32 * 132];   // phase1 staging, then i_n, then n
  __shared__ float Bs[32 * 128];    // weight K-chunk
  const int t = threadIdx.x;
  const int e0 = blockIdx.x * 32;   // exact: 500000 = 32 * 15625
  const int og = t & 31, eg = t >> 5;
  float acc[4][4];

  // ---- phase 1: x = [re|hs|hd] @ W2t  (K = 384) ----
#pragma unroll
  for (int i = 0; i < 4; ++i)
#pragma unroll
    for (int j = 0; j < 4; ++j) acc[i][j] = 0.f;
  for (int comp = 0; comp < 3; ++comp) {
    __syncthreads();  // protect N_s (read by previous comp's MACs)
    for (int idx = t; idx < 32 * 32; idx += 256) {
      int e = idx >> 5, c4 = idx & 31;
      int ge = e0 + e;
      const float* rowp;
      if (comp == 0)      rowp = rel_emb + (size_t)ety[ge] * DIM;
      else if (comp == 1) rowp = nf + (size_t)src[ge] * DIM;
      else                rowp = nf + (size_t)dst[ge] * DIM;
      *(float4*)(N_s + e * 132 + c4 * 4) = *(const float4*)(rowp + c4 * 4);
    }
    for (int c = 0; c < 4; ++c) {
      __syncthreads();  // Bs safe to overwrite; (c==0) N_s writes visible after next sync
      stageB(Bs, W2t, comp * 128 + c * 32, 128, 0, t);
      __syncthreads();
      mac32(N_s, c * 32, Bs, eg, og, acc);
    }
  }
  __syncthreads();  // all phase-1 reads of N_s/Bs done
  {
    float4 bv = *(const float4*)(b2 + og * 4);
#pragma unroll
    for (int i = 0; i < 4; ++i) {
      float4 x;
      x.x = acc[i][0] + bv.x; x.y = acc[i][1] + bv.y;
      x.z = acc[i][2] + bv.z; x.w = acc[i][3] + bv.w;
      *(float4*)(X_s + (eg * 4 + i) * 132 + og * 4) = x;
    }
  }
  for (int idx = t; idx < 32 * 32; idx += 256) {  // stage h = ef
    int e = idx >> 5, c4 = idx & 31;
    *(float4*)(A_s + e * 132 + c4 * 4) =
        *(const float4*)(ef + (size_t)(e0 + e) * DIM + c4 * 4);
  }

  // ---- gate i_n = X @ Wih_n^T  (K = 128, cols 256..384) -> N_s ----
#pragma unroll
  for (int i = 0; i < 4; ++i)
#pragma unroll
    for (int j = 0; j < 4; ++j) acc[i][j] = 0.f;
  for (int c = 0; c < 4; ++c) {
    __syncthreads();  // also makes X_s / A_s writes visible at c==0
    stageB(Bs, Wiht, c * 32, 384, 256, t);
    __syncthreads();
    mac32(X_s, c * 32, Bs, eg, og, acc);
  }
  {
    float4 bi = *(const float4*)(bih + 256 + og * 4);
#pragma unroll
    for (int i = 0; i < 4; ++i) {
      N_s[(eg * 4 + i) * 132 + og * 4 + 0] = acc[i][0] + bi.x;
      N_s[(eg * 4 + i) * 132 + og * 4 + 1] = acc[i][1] + bi.y;
      N_s[(eg * 4 + i) * 132 + og * 4 + 2] = acc[i][2] + bi.z;
      N_s[(eg * 4 + i) * 132 + og * 4 + 3] = acc[i][3] + bi.w;
    }
  }

  // ---- gate r = sigm(X@Wih_r^T + h@Whh_r^T + b)  (K = 256, cols 0..128) ----
  float r_g[4][4];
#pragma unroll
  for (int i = 0; i < 4; ++i)
#pragma unroll
    for (int j = 0; j < 4; ++j) acc[i][j] = 0.f;
  for (int c = 0; c < 8; ++c) {
    __syncthreads();
    stageB(Bs, c < 4 ? Wiht : Whht, (c & 3) * 32, 384, 0, t);
    __syncthreads();
    mac32(c < 4 ? X_s : A_s, (c & 3) * 32, Bs, eg, og, acc);
  }
  {
    float4 bi = *(const float4*)(bih + og * 4);
    float4 bh = *(const float4*)(bhh + og * 4);
#pragma unroll
    for (int i = 0; i < 4; ++i) {
      r_g[i][0] = sigm(acc[i][0] + bi.x + bh.x);
      r_g[i][1] = sigm(acc[i][1] + bi.y + bh.y);
      r_g[i][2] = sigm(acc[i][2] + bi.z + bh.z);
      r_g[i][3] = sigm(acc[i][3] + bi.w + bh.w);
    }
  }

  // ---- gate h_n = h @ Whh_n^T  (K = 128, cols 256..384); n -> N_s ----
#pragma unroll
  for (int i = 0; i < 4; ++i)
#pragma unroll
    for (int j = 0; j < 4; ++j) acc[i][j] = 0.f;
  for (int c = 0; c < 4; ++c) {
    __syncthreads();
    stageB(Bs, Whht, c * 32, 384, 256, t);
    __syncthreads();
    mac32(A_s, c * 32, Bs, eg, og, acc);
  }
  {
    float4 bh = *(const float4*)(bhh + 256 + og * 4);
#pragma unroll
    for (int i = 0; i < 4; ++i) {
      float* np = N_s + (eg * 4 + i) * 132 + og * 4;  // own cells: no sync needed
      np[0] = tanh_fast(np[0] + r_g[i][0] * (acc[i][0] + bh.x));
      np[1] = tanh_fast(np[1] + r_g[i][1] * (acc[i][1] + bh.y));
      np[2] = tanh_fast(np[2] + r_g[i][2] * (acc[i][2] + bh.z));
      np[3] = tanh_fast(np[3] + r_g[i][3] * (acc[i][3] + bh.w));
    }
  }

  // ---- gate z (K = 256, cols 128..256); combine + store ----
#pragma unroll
  for (int i = 0; i < 4; ++i)
#pragma unroll
    for (int j = 0; j < 4; ++j) acc[i][j] = 0.f;
  for (int c = 0; c < 8; ++c) {
    __syncthreads();
    stageB(Bs, c < 4 ? Wiht : Whht, (c & 3) * 32, 384, 128, t);
    __syncthreads();
    mac32(c < 4 ? X_s : A_s, (c & 3) * 32, Bs, eg, og, acc);
  }
  {
    float4 bi = *(const float4*)(bih + 128 + og * 4);
    float4 bh = *(const float4*)(bhh + 128 + og * 4);
#pragma unroll
    for (int i = 0; i < 4; ++i) {
      const float* np = N_s + (eg * 4 + i) * 132 + og * 4;
      const float* hp = A_s + (eg * 4 + i) * 132 + og * 4;
      float4 res;
      float z0 = sigm(acc[i][0] + bi.x + bh.x);
      float z1 = sigm(acc[i][1] + bi.y + bh.y);
      float z2 = sigm(acc[i][2] + bi.z + bh.z);
      float z3 = sigm(acc[i][3] + bi.w + bh.w);
      res.x = (1.f - z0) * np[0] + z0 * hp[0];
      res.y = (1.f - z1) * np[1] + z1 * hp[1];
      res.z = (1.f - z2) * np[2] + z2 * hp[2];
      res.w = (1.f - z3) * np[3] + z3 * hp[3];
      *(float4*)(ef + (size_t)(e0 + eg * 4 + i) * DIM + og * 4) = res;
    }
  }
}

// ---------------------------------------------------------------- node update
__launch_bounds__(256, 2)
__global__ void k_node(const float* __restrict__ nf, const float* __restrict__ node_acc,
                       const int* __restrict__ deg, const float* __restrict__ W3t,
                       const float* __restrict__ b3, float* __restrict__ out) {
  __shared__ float A_s[64 * 132];
  __shared__ float Bs[64 * 128];
  const int t = threadIdx.x;
  const int n0 = blockIdx.x * 64;
  const int og = t & 15, ng = t >> 4;
  float acc[4][8];
#pragma unroll
  for (int i = 0; i < 4; ++i)
#pragma unroll
    for (int j = 0; j < 8; ++j) acc[i][j] = 0.f;

  for (int idx = t; idx < 64 * 32; idx += 256) {
    int e = idx >> 5, c4 = idx & 31;
    int gn = n0 + e;
    float4 v = make_float4(0.f, 0.f, 0.f, 0.f);
    if (gn < N_NODESC) v = *(const float4*)(nf + (size_t)gn * DIM + c4 * 4);
    *(float4*)(A_s + e * 132 + c4 * 4) = v;
  }
  for (int kc = 0; kc < 2; ++kc) {
    __syncthreads();
    for (int idx = t; idx < 64 * 32; idx += 256) {
      int kk = idx >> 5, c4 = idx & 31;
      *(float4*)(Bs + kk * 128 + c4 * 4) =
          *(const float4*)(W3t + (size_t)(kc * 64 + kk) * DIM + c4 * 4);
    }
    __syncthreads();
    const float* arow = A_s + (ng * 4) * 132 + kc * 64;
    for (int k4 = 0; k4 < 16; ++k4) {
      float4 a[4];
#pragma unroll
      for (int i = 0; i < 4; ++i) a[i] = *(const float4*)(arow + i * 132 + k4 * 4);
#pragma unroll
      for (int kk = 0; kk < 4; ++kk) {
        const float* brow = Bs + (k4 * 4 + kk) * 128 + og * 8;
        float4 b0 = *(const float4*)(brow);
        float4 b1v = *(const float4*)(brow + 4);
#pragma unroll
        for (int i = 0; i < 4; ++i) {
          float av = ((const float*)&a[i])[kk];
          acc[i][0] += av * b0.x;  acc[i][1] += av * b0.y;
          acc[i][2] += av * b0.z;  acc[i][3] += av * b0.w;
          acc[i][4] += av * b1v.x; acc[i][5] += av * b1v.y;
          acc[i][6] += av * b1v.z; acc[i][7] += av * b1v.w;
        }
      }
    }
  }
  float bv[8];
#pragma unroll
  for (int j = 0; j < 8; ++j) bv[j] = b3[og * 8 + j];
#pragma unroll
  for (int i = 0; i < 4; ++i) {
    int gn = n0 + ng * 4 + i;
    if (gn < N_NODESC) {
      float inv = 1.f / (float)max(deg[gn], 1);
      const float* nap = node_acc + (size_t)gn * DIM + og * 8;
      float* op = out + (size_t)gn * DIM + og * 8;
#pragma unroll
      for (int j = 0; j < 8; ++j) {
        float pre = acc[i][j] + bv[j] + nap[j] * inv;
        op[j] = (pre >= 0.f) ? pre : RRELU * pre;
      }
    }
  }
}

// ---------------------------------------------------------------- launch
extern "C" void kernel_launch(void* const* d_in, const int* in_sizes, int n_in,
                              void* d_out, int out_size, void* d_ws, size_t ws_size,
                              hipStream_t stream) {
  const float* nf0 = (const float*)d_in[0];
  float* ef = (float*)d_in[1];
  const int* src = (const int*)d_in[2];
  const int* dst = (const int*)d_in[3];
  const int* ety = (const int*)d_in[4];
  const float* W1 = (const float*)d_in[6];
  const float* b1 = (const float*)d_in[7];
  const float* W2 = (const float*)d_in[8];
  const float* b2 = (const float*)d_in[9];
  const float* W3 = (const float*)d_in[10];
  const float* b3 = (const float*)d_in[11];
  const float* Wih = (const float*)d_in[12];
  const float* Whh = (const float*)d_in[13];
  const float* bih = (const float*)d_in[14];
  const float* bhh = (const float*)d_in[15];
  float* out = (float*)d_out;

  char* wsb = (char*)d_ws;
  size_t off = 0;
  auto alloc = [&](size_t b) {
    char* p = wsb + off;
    off = (off + b + 255) & ~(size_t)255;
    return p;
  };
  unsigned* mask  = (unsigned*)alloc(sizeof(unsigned) * NREL * MWORDS);
  int* deg        = (int*)alloc(sizeof(int) * N_NODESC);
  float* rel_sum  = (float*)alloc(sizeof(float) * NREL * DIM);
  int* cnt        = (int*)alloc(sizeof(int) * NREL);
  float* rel_emb  = (float*)alloc(sizeof(float) * NREL * DIM);
  float* node_acc = (float*)alloc(sizeof(float) * N_NODESC * DIM);
  float* W1t      = (float*)alloc(sizeof(float) * 2 * 384 * DIM);
  float* W2t      = (float*)alloc(sizeof(float) * 384 * DIM);
  float* W3t      = (float*)alloc(sizeof(float) * 2 * DIM * DIM);
  float* Wiht     = (float*)alloc(sizeof(float) * DIM * 384);
  float* Whht     = (float*)alloc(sizeof(float) * DIM * 384);

  hipMemsetAsync(mask, 0, sizeof(unsigned) * NREL * MWORDS, stream);
  hipMemsetAsync(deg, 0, sizeof(int) * N_NODESC, stream);
  k_mask_deg<<<(N_EDGESC + 255) / 256, 256, 0, stream>>>(src, dst, ety, mask, deg);

  // weight transposes (Wt[k][o] = W[o][k])
  k_transpose<<<192, 256, 0, stream>>>(W1, W1t, 128, 384);
  k_transpose<<<192, 256, 0, stream>>>(W1 + 128 * 384, W1t + 384 * 128, 128, 384);
  k_transpose<<<192, 256, 0, stream>>>(W2, W2t, 128, 384);
  k_transpose<<<64, 256, 0, stream>>>(W3, W3t, 128, 128);
  k_transpose<<<64, 256, 0, stream>>>(W3 + 128 * 128, W3t + 128 * 128, 128, 128);
  k_transpose<<<192, 256, 0, stream>>>(Wih, Wiht, 384, 128);
  k_transpose<<<192, 256, 0, stream>>>(Whh, Whht, 384, 128);

  for (int l = 0; l < 2; ++l) {
    const float* nfl = l ? (const float*)out : nf0;
    hipMemsetAsync(rel_sum, 0, sizeof(float) * NREL * DIM, stream);
    hipMemsetAsync(cnt, 0, sizeof(int) * NREL, stream);
    hipMemsetAsync(node_acc, 0, sizeof(float) * N_NODESC * DIM, stream);
    k_rel_reduce<<<NREL * RCHUNK, 128, 0, stream>>>(nfl, mask, rel_sum, cnt);
    k_rel_div<<<(NREL * DIM + 255) / 256, 256, 0, stream>>>(rel_sum, cnt, rel_emb);
    k_edge_msg<<<(N_EDGESC + 63) / 64, 256, 0, stream>>>(
        nfl, ef, rel_emb, src, dst, ety,
        W1t + (size_t)l * 384 * DIM, b1 + l * DIM, node_acc);
    if (l == 0) {
      k_edge_gru<<<N_EDGESC / 32, 256, 0, stream>>>(
          nfl, ef, rel_emb, src, dst, ety, W2t, b2, Wiht, Whht, bih, bhh);
    }
    k_node<<<(N_NODESC + 63) / 64, 256, 0, stream>>>(
        nfl, node_acc, deg, W3t + (size_t)l * DIM * DIM, b3 + l * DIM, out);
  }
}

// Round 4
// 2128.005 us; speedup vs baseline: 18.6653x; 3.5013x over previous
//
#include <hip/hip_runtime.h>
#include <hip/hip_bf16.h>

#define N_NODESC 50000
#define N_EDGESC 500000
#define DIM 128
#define NREL 200
#define MWORDS 1563   /* ceil(50000/32) */
#define RRELU 0.22916666666666666f
#define RCHUNK 8

typedef float f32x4 __attribute__((ext_vector_type(4)));
typedef short bf16x8 __attribute__((ext_vector_type(8)));   // 8 bf16 in 4 VGPRs
typedef unsigned int u32x4 __attribute__((ext_vector_type(4)));
typedef unsigned short ushort;

__device__ __forceinline__ float sigm(float x) { return 1.f / (1.f + __expf(-x)); }
__device__ __forceinline__ float tanh_fast(float x) {
  x = fminf(fmaxf(x, -15.f), 15.f);
  float e2 = __expf(-2.f * x);
  return (1.f - e2) / (1.f + e2);
}
__device__ __forceinline__ ushort f2bf(float f) {          // RNE fp32->bf16
  unsigned u = __float_as_uint(f);
  u += 0x7FFFu + ((u >> 16) & 1u);
  return (ushort)(u >> 16);
}
__device__ __forceinline__ float bf2f(ushort h) {
  return __uint_as_float((unsigned)h << 16);
}

#define MFMA16(a, b, c) __builtin_amdgcn_mfma_f32_16x16x32_bf16((a), (b), (c), 0, 0, 0)

// ---------------------------------------------------------------- mask + deg
__global__ void k_mask_deg(const int* __restrict__ src, const int* __restrict__ dst,
                           const int* __restrict__ ety, unsigned* __restrict__ mask,
                           int* __restrict__ deg) {
  int e = blockIdx.x * blockDim.x + threadIdx.x;
  if (e >= N_EDGESC) return;
  int r = ety[e], s = src[e], d = dst[e];
  atomicOr(&mask[r * MWORDS + (s >> 5)], 1u << (s & 31));
  atomicOr(&mask[r * MWORDS + (d >> 5)], 1u << (d & 31));
  atomicAdd(&deg[d], 1);
}

// ---------------------------------------------------------------- transpose (W3 only)
__global__ void k_transpose(const float* __restrict__ in, float* __restrict__ out,
                            int R, int C) {
  int i = blockIdx.x * blockDim.x + threadIdx.x;
  if (i >= R * C) return;
  int r = i / C, c = i - r * C;
  out[c * R + r] = in[i];
}

// ---------------------------------------------------------------- fp32 -> bf16 hi/lo planes
__global__ void k_split(const float* __restrict__ in, ushort* __restrict__ hi,
                        ushort* __restrict__ lo, int n) {
  int i = blockIdx.x * blockDim.x + threadIdx.x;
  if (i >= n) return;
  float f = in[i];
  ushort h = f2bf(f);
  hi[i] = h;
  lo[i] = f2bf(f - bf2f(h));
}

// ---------------------------------------------------------------- rel reduce
__global__ void k_rel_reduce(const float* __restrict__ nf, const unsigned* __restrict__ mask,
                             float* __restrict__ rel_sum, int* __restrict__ cnt) {
  int rel = blockIdx.x / RCHUNK;
  int chunk = blockIdx.x - rel * RCHUNK;
  int j = threadIdx.x;
  const int wpc = (MWORDS + RCHUNK - 1) / RCHUNK;
  int w0 = chunk * wpc;
  int w1 = min(MWORDS, w0 + wpc);
  float acc = 0.f;
  int c = 0;
  for (int w = w0; w < w1; ++w) {
    unsigned word = mask[rel * MWORDS + w];
    c += __popc(word);
    while (word) {
      int b = __ffs(word) - 1;
      word &= word - 1;
      acc += nf[(size_t)(w * 32 + b) * DIM + j];
    }
  }
  unsafeAtomicAdd(&rel_sum[rel * DIM + j], acc);
  if (j == 0) atomicAdd(&cnt[rel], c);
}

__global__ void k_rel_div(const float* __restrict__ rel_sum, const int* __restrict__ cnt,
                          float* __restrict__ rel_emb) {
  int i = blockIdx.x * blockDim.x + threadIdx.x;
  if (i >= NREL * DIM) return;
  int r = i / DIM;
  int c = cnt[r];
  rel_emb[i] = (c > 0) ? rel_sum[i] / (float)c : 0.f;
}

// ---------------------------------------------------------------- MFMA staging helpers
// Stage 8 fp32 (one quarter-row of a 64x32 chunk) as bf16 hi/lo into LDS (stride 40).
__device__ __forceinline__ void stage_rowchunk(const float* __restrict__ rowp,
                                               ushort* __restrict__ SH,
                                               ushort* __restrict__ SL, int r, int q) {
  float4 v0 = *(const float4*)(rowp);
  float4 v1 = *(const float4*)(rowp + 4);
  float f[8] = {v0.x, v0.y, v0.z, v0.w, v1.x, v1.y, v1.z, v1.w};
  u32x4 hw, lw;
#pragma unroll
  for (int j = 0; j < 4; ++j) {
    ushort ha = f2bf(f[2 * j]), hb = f2bf(f[2 * j + 1]);
    float ra = f[2 * j] - bf2f(ha), rb = f[2 * j + 1] - bf2f(hb);
    hw[j] = (unsigned)ha | ((unsigned)hb << 16);
    lw[j] = (unsigned)f2bf(ra) | ((unsigned)f2bf(rb) << 16);
  }
  *(u32x4*)(SH + r * 40 + q * 8) = hw;
  *(u32x4*)(SL + r * 40 + q * 8) = lw;
}

// Stage a [128 n][32 k] weight chunk from pre-split bf16 planes into LDS (stride 40).
__device__ __forceinline__ void stage_wchunk(const ushort* __restrict__ Wh,
                                             const ushort* __restrict__ Wl, int Kw,
                                             int nbase, int kg,
                                             ushort* __restrict__ SBh,
                                             ushort* __restrict__ SBl, int t) {
  int n = t >> 1, hf = t & 1;
  size_t off = (size_t)(nbase + n) * Kw + kg + hf * 16;
  u32x4 a = *(const u32x4*)(Wh + off);
  u32x4 b = *(const u32x4*)(Wh + off + 8);
  *(u32x4*)(SBh + n * 40 + hf * 16) = a;
  *(u32x4*)(SBh + n * 40 + hf * 16 + 8) = b;
  u32x4 c = *(const u32x4*)(Wl + off);
  u32x4 d = *(const u32x4*)(Wl + off + 8);
  *(u32x4*)(SBl + n * 40 + hf * 16) = c;
  *(u32x4*)(SBl + n * 40 + hf * 16 + 8) = d;
}

// One K=32 MFMA step: M=64 (4 m-subtiles), wave's N=32 (2 n-tiles), 3-term split.
__device__ __forceinline__ void mfma_chunk(const ushort* __restrict__ Ah,
                                           const ushort* __restrict__ Al, int astride,
                                           int akoff, const ushort* __restrict__ Bh,
                                           const ushort* __restrict__ Bl, int w, int lq,
                                           int lr, f32x4 acc[4][2]) {
  bf16x8 bh[2], bl[2];
#pragma unroll
  for (int nt = 0; nt < 2; ++nt) {
    int bo = (w * 32 + nt * 16 + lr) * 40 + lq * 8;
    bh[nt] = *(const bf16x8*)(Bh + bo);
    bl[nt] = *(const bf16x8*)(Bl + bo);
  }
#pragma unroll
  for (int ms = 0; ms < 4; ++ms) {
    int ao = (ms * 16 + lr) * astride + akoff + lq * 8;
    bf16x8 ah = *(const bf16x8*)(Ah + ao);
    bf16x8 al = *(const bf16x8*)(Al + ao);
#pragma unroll
    for (int nt = 0; nt < 2; ++nt) {
      acc[ms][nt] = MFMA16(ah, bh[nt], acc[ms][nt]);
      acc[ms][nt] = MFMA16(al, bh[nt], acc[ms][nt]);
      acc[ms][nt] = MFMA16(ah, bl[nt], acc[ms][nt]);
    }
  }
}

// ---------------------------------------------------------------- edge msg (MFMA) + scatter
// msg = [re|hs|ef] @ W1^T + b1 ; atomic scatter rows to node_acc[dst].
__launch_bounds__(256, 4)
__global__ void k_edge_msg(const float* __restrict__ nf, const float* __restrict__ ef,
                           const float* __restrict__ rel_emb,
                           const int* __restrict__ src, const int* __restrict__ dst,
                           const int* __restrict__ ety,
                           const ushort* __restrict__ W1h, const ushort* __restrict__ W1l,
                           const float* __restrict__ bias, float* __restrict__ node_acc) {
  __shared__ ushort SA_hi[64 * 40], SA_lo[64 * 40];
  __shared__ ushort SB_hi[128 * 40], SB_lo[128 * 40];
  const int t = threadIdx.x;
  const int e0 = blockIdx.x * 64;
  const int w = t >> 6, l = t & 63, lq = l >> 4, lr = l & 15;
  const int r = t >> 2, q = t & 3;
  const int ge = min(e0 + r, N_EDGESC - 1);
  const int iety = ety[ge], isrc = src[ge];

  f32x4 acc[4][2];
#pragma unroll
  for (int i = 0; i < 4; ++i)
#pragma unroll
    for (int j = 0; j < 2; ++j) acc[i][j] = (f32x4){0.f, 0.f, 0.f, 0.f};

  for (int c = 0; c < 12; ++c) {
    __syncthreads();
    int comp = c >> 2, ko = (c & 3) * 32;
    const float* rowp;
    if (comp == 0)      rowp = rel_emb + (size_t)iety * DIM + ko;
    else if (comp == 1) rowp = nf + (size_t)isrc * DIM + ko;
    else                rowp = ef + (size_t)ge * DIM + ko;
    stage_rowchunk(rowp + q * 8, SA_hi, SA_lo, r, q);
    stage_wchunk(W1h, W1l, 384, 0, c * 32, SB_hi, SB_lo, t);
    __syncthreads();
    mfma_chunk(SA_hi, SA_lo, 40, 0, SB_hi, SB_lo, w, lq, lr, acc);
  }

#pragma unroll
  for (int nt = 0; nt < 2; ++nt) {
    int col = w * 32 + nt * 16 + lr;
    float bv = bias[col];
#pragma unroll
    for (int ms = 0; ms < 4; ++ms)
#pragma unroll
      for (int rg = 0; rg < 4; ++rg) {
        int row = ms * 16 + lq * 4 + rg;
        int geo = e0 + row;
        if (geo < N_EDGESC)
          unsafeAtomicAdd(node_acc + (size_t)dst[geo] * DIM + col, acc[ms][nt][rg] + bv);
      }
  }
}

// ---------------------------------------------------------------- edge_msg + GRU (layer 0, MFMA)
// X = [re|hs|hd]@W2^T + b2 ; gates via Wih/Whh ; new_e in place into ef.
__launch_bounds__(256, 2)
__global__ void k_edge_gru(const float* __restrict__ nf, float* __restrict__ ef,
                           const float* __restrict__ rel_emb,
                           const int* __restrict__ src, const int* __restrict__ dst,
                           const int* __restrict__ ety,
                           const ushort* __restrict__ W2h, const ushort* __restrict__ W2l,
                           const ushort* __restrict__ Wihh, const ushort* __restrict__ Wihl,
                           const ushort* __restrict__ Whhh, const ushort* __restrict__ Whhl,
                           const float* __restrict__ b2, const float* __restrict__ bih,
                           const float* __restrict__ bhh) {
  __shared__ ushort SA_hi[64 * 40], SA_lo[64 * 40];      // gathered A / h chunks
  __shared__ ushort SB_hi[128 * 40], SB_lo[128 * 40];    // weight chunk
  __shared__ ushort XH[64 * 136], XL[64 * 136];          // X = edge_msg, bf16 hi/lo
  const int t = threadIdx.x;
  const int e0 = blockIdx.x * 64;
  const int w = t >> 6, l = t & 63, lq = l >> 4, lr = l & 15;
  const int r = t >> 2, q = t & 3;
  const int ge = min(e0 + r, N_EDGESC - 1);
  const int iety = ety[ge], isrc = src[ge], idst = dst[ge];

  // ---- P1: X = [re|hs|hd] @ W2^T (K=384) ----
  f32x4 accx[4][2];
#pragma unroll
  for (int i = 0; i < 4; ++i)
#pragma unroll
    for (int j = 0; j < 2; ++j) accx[i][j] = (f32x4){0.f, 0.f, 0.f, 0.f};
  for (int c = 0; c < 12; ++c) {
    __syncthreads();
    int comp = c >> 2, ko = (c & 3) * 32;
    const float* rowp;
    if (comp == 0)      rowp = rel_emb + (size_t)iety * DIM + ko;
    else if (comp == 1) rowp = nf + (size_t)isrc * DIM + ko;
    else                rowp = nf + (size_t)idst * DIM + ko;
    stage_rowchunk(rowp + q * 8, SA_hi, SA_lo, r, q);
    stage_wchunk(W2h, W2l, 384, 0, c * 32, SB_hi, SB_lo, t);
    __syncthreads();
    mfma_chunk(SA_hi, SA_lo, 40, 0, SB_hi, SB_lo, w, lq, lr, accx);
  }
  // write X (+b2) as bf16 hi/lo planes
#pragma unroll
  for (int nt = 0; nt < 2; ++nt) {
    int col = w * 32 + nt * 16 + lr;
    float bv = b2[col];
#pragma unroll
    for (int ms = 0; ms < 4; ++ms)
#pragma unroll
      for (int rg = 0; rg < 4; ++rg) {
        int row = ms * 16 + lq * 4 + rg;
        float x = accx[ms][nt][rg] + bv;
        ushort h = f2bf(x);
        XH[row * 136 + col] = h;
        XL[row * 136 + col] = f2bf(x - bf2f(h));
      }
  }

  // ---- Wih pass: gi_r, gi_z, gi_n from X (K=128) ----
  f32x4 arz0[4][2], arz1[4][2], ain[4][2], ahn[4][2];
#pragma unroll
  for (int i = 0; i < 4; ++i)
#pragma unroll
    for (int j = 0; j < 2; ++j) {
      arz0[i][j] = (f32x4){0.f, 0.f, 0.f, 0.f};
      arz1[i][j] = (f32x4){0.f, 0.f, 0.f, 0.f};
      ain[i][j]  = (f32x4){0.f, 0.f, 0.f, 0.f};
      ahn[i][j]  = (f32x4){0.f, 0.f, 0.f, 0.f};
    }
#pragma unroll
  for (int gg = 0; gg < 3; ++gg) {
    for (int kc = 0; kc < 4; ++kc) {
      __syncthreads();
      stage_wchunk(Wihh, Wihl, 128, gg * 128, kc * 32, SB_hi, SB_lo, t);
      __syncthreads();
      mfma_chunk(XH, XL, 136, kc * 32, SB_hi, SB_lo, w, lq, lr,
                 gg == 0 ? arz0 : (gg == 1 ? arz1 : ain));
    }
  }

  // ---- Whh pass: gh_r, gh_z, gh_n from h = ef (K=128) ----
  for (int kc = 0; kc < 4; ++kc) {
    __syncthreads();
    stage_rowchunk(ef + (size_t)ge * DIM + kc * 32 + q * 8, SA_hi, SA_lo, r, q);
    stage_wchunk(Whhh, Whhl, 128, 0, kc * 32, SB_hi, SB_lo, t);
    __syncthreads();
    mfma_chunk(SA_hi, SA_lo, 40, 0, SB_hi, SB_lo, w, lq, lr, arz0);
    __syncthreads();
    stage_wchunk(Whhh, Whhl, 128, 128, kc * 32, SB_hi, SB_lo, t);
    __syncthreads();
    mfma_chunk(SA_hi, SA_lo, 40, 0, SB_hi, SB_lo, w, lq, lr, arz1);
    __syncthreads();
    stage_wchunk(Whhh, Whhl, 128, 256, kc * 32, SB_hi, SB_lo, t);
    __syncthreads();
    mfma_chunk(SA_hi, SA_lo, 40, 0, SB_hi, SB_lo, w, lq, lr, ahn);
  }

  // ---- gates + blend + store ----
#pragma unroll
  for (int nt = 0; nt < 2; ++nt) {
    int col = w * 32 + nt * 16 + lr;
    float bir = bih[col],       bhr = bhh[col];
    float biz = bih[128 + col], bhz = bhh[128 + col];
    float bin = bih[256 + col], bhn = bhh[256 + col];
#pragma unroll
    for (int ms = 0; ms < 4; ++ms)
#pragma unroll
      for (int rg = 0; rg < 4; ++rg) {
        int row = ms * 16 + lq * 4 + rg;
        int geo = e0 + row;
        if (geo < N_EDGESC) {
          float rr = sigm(arz0[ms][nt][rg] + bir + bhr);
          float zz = sigm(arz1[ms][nt][rg] + biz + bhz);
          float nn = tanh_fast(ain[ms][nt][rg] + bin + rr * (ahn[ms][nt][rg] + bhn));
          float hv = ef[(size_t)geo * DIM + col];
          ef[(size_t)geo * DIM + col] = (1.f - zz) * nn + zz * hv;
        }
      }
  }
}

// ---------------------------------------------------------------- node update (fp32, small)
__launch_bounds__(256, 2)
__global__ void k_node(const float* __restrict__ nf, const float* __restrict__ node_acc,
                       const int* __restrict__ deg, const float* __restrict__ W3t,
                       const float* __restrict__ b3, float* __restrict__ out) {
  __shared__ float A_s[64 * 132];
  __shared__ float Bs[64 * 128];
  const int t = threadIdx.x;
  const int n0 = blockIdx.x * 64;
  const int og = t & 15, ng = t >> 4;
  float acc[4][8];
#pragma unroll
  for (int i = 0; i < 4; ++i)
#pragma unroll
    for (int j = 0; j < 8; ++j) acc[i][j] = 0.f;

  for (int idx = t; idx < 64 * 32; idx += 256) {
    int e = idx >> 5, c4 = idx & 31;
    int gn = n0 + e;
    float4 v = make_float4(0.f, 0.f, 0.f, 0.f);
    if (gn < N_NODESC) v = *(const float4*)(nf + (size_t)gn * DIM + c4 * 4);
    *(float4*)(A_s + e * 132 + c4 * 4) = v;
  }
  for (int kc = 0; kc < 2; ++kc) {
    __syncthreads();
    for (int idx = t; idx < 64 * 32; idx += 256) {
      int kk = idx >> 5, c4 = idx & 31;
      *(float4*)(Bs + kk * 128 + c4 * 4) =
          *(const float4*)(W3t + (size_t)(kc * 64 + kk) * DIM + c4 * 4);
    }
    __syncthreads();
    const float* arow = A_s + (ng * 4) * 132 + kc * 64;
    for (int k4 = 0; k4 < 16; ++k4) {
      float4 a[4];
#pragma unroll
      for (int i = 0; i < 4; ++i) a[i] = *(const float4*)(arow + i * 132 + k4 * 4);
#pragma unroll
      for (int kk = 0; kk < 4; ++kk) {
        const float* brow = Bs + (k4 * 4 + kk) * 128 + og * 8;
        float4 b0 = *(const float4*)(brow);
        float4 b1v = *(const float4*)(brow + 4);
#pragma unroll
        for (int i = 0; i < 4; ++i) {
          float av = ((const float*)&a[i])[kk];
          acc[i][0] += av * b0.x;  acc[i][1] += av * b0.y;
          acc[i][2] += av * b0.z;  acc[i][3] += av * b0.w;
          acc[i][4] += av * b1v.x; acc[i][5] += av * b1v.y;
          acc[i][6] += av * b1v.z; acc[i][7] += av * b1v.w;
        }
      }
    }
  }
  float bv[8];
#pragma unroll
  for (int j = 0; j < 8; ++j) bv[j] = b3[og * 8 + j];
#pragma unroll
  for (int i = 0; i < 4; ++i) {
    int gn = n0 + ng * 4 + i;
    if (gn < N_NODESC) {
      float inv = 1.f / (float)max(deg[gn], 1);
      const float* nap = node_acc + (size_t)gn * DIM + og * 8;
      float* op = out + (size_t)gn * DIM + og * 8;
#pragma unroll
      for (int j = 0; j < 8; ++j) {
        float pre = acc[i][j] + bv[j] + nap[j] * inv;
        op[j] = (pre >= 0.f) ? pre : RRELU * pre;
      }
    }
  }
}

// ---------------------------------------------------------------- launch
extern "C" void kernel_launch(void* const* d_in, const int* in_sizes, int n_in,
                              void* d_out, int out_size, void* d_ws, size_t ws_size,
                              hipStream_t stream) {
  const float* nf0 = (const float*)d_in[0];
  float* ef = (float*)d_in[1];
  const int* src = (const int*)d_in[2];
  const int* dst = (const int*)d_in[3];
  const int* ety = (const int*)d_in[4];
  const float* W1 = (const float*)d_in[6];
  const float* b1 = (const float*)d_in[7];
  const float* W2 = (const float*)d_in[8];
  const float* b2 = (const float*)d_in[9];
  const float* W3 = (const float*)d_in[10];
  const float* b3 = (const float*)d_in[11];
  const float* Wih = (const float*)d_in[12];
  const float* Whh = (const float*)d_in[13];
  const float* bih = (const float*)d_in[14];
  const float* bhh = (const float*)d_in[15];
  float* out = (float*)d_out;

  char* wsb = (char*)d_ws;
  size_t off = 0;
  auto alloc = [&](size_t b) {
    char* p = wsb + off;
    off = (off + b + 255) & ~(size_t)255;
    return p;
  };
  unsigned* mask  = (unsigned*)alloc(sizeof(unsigned) * NREL * MWORDS);
  int* deg        = (int*)alloc(sizeof(int) * N_NODESC);
  float* rel_sum  = (float*)alloc(sizeof(float) * NREL * DIM);
  int* cnt        = (int*)alloc(sizeof(int) * NREL);
  float* rel_emb  = (float*)alloc(sizeof(float) * NREL * DIM);
  float* node_acc = (float*)alloc(sizeof(float) * N_NODESC * DIM);
  float* W3t      = (float*)alloc(sizeof(float) * 2 * DIM * DIM);
  ushort* W1h     = (ushort*)alloc(sizeof(ushort) * 2 * 128 * 384);
  ushort* W1l     = (ushort*)alloc(sizeof(ushort) * 2 * 128 * 384);
  ushort* W2h     = (ushort*)alloc(sizeof(ushort) * 128 * 384);
  ushort* W2l     = (ushort*)alloc(sizeof(ushort) * 128 * 384);
  ushort* Wihh    = (ushort*)alloc(sizeof(ushort) * 384 * 128);
  ushort* Wihl    = (ushort*)alloc(sizeof(ushort) * 384 * 128);
  ushort* Whhh    = (ushort*)alloc(sizeof(ushort) * 384 * 128);
  ushort* Whhl    = (ushort*)alloc(sizeof(ushort) * 384 * 128);

  hipMemsetAsync(mask, 0, sizeof(unsigned) * NREL * MWORDS, stream);
  hipMemsetAsync(deg, 0, sizeof(int) * N_NODESC, stream);
  k_mask_deg<<<(N_EDGESC + 255) / 256, 256, 0, stream>>>(src, dst, ety, mask, deg);

  // weight prep: W3 fp32 transpose (k_node), bf16 hi/lo planes for MFMA kernels
  k_transpose<<<64, 256, 0, stream>>>(W3, W3t, 128, 128);
  k_transpose<<<64, 256, 0, stream>>>(W3 + 128 * 128, W3t + 128 * 128, 128, 128);
  k_split<<<(2 * 128 * 384 + 255) / 256, 256, 0, stream>>>(W1, W1h, W1l, 2 * 128 * 384);
  k_split<<<(128 * 384 + 255) / 256, 256, 0, stream>>>(W2, W2h, W2l, 128 * 384);
  k_split<<<(384 * 128 + 255) / 256, 256, 0, stream>>>(Wih, Wihh, Wihl, 384 * 128);
  k_split<<<(384 * 128 + 255) / 256, 256, 0, stream>>>(Whh, Whhh, Whhl, 384 * 128);

  const int egrid = (N_EDGESC + 63) / 64;
  for (int l = 0; l < 2; ++l) {
    const float* nfl = l ? (const float*)out : nf0;
    hipMemsetAsync(rel_sum, 0, sizeof(float) * NREL * DIM, stream);
    hipMemsetAsync(cnt, 0, sizeof(int) * NREL, stream);
    hipMemsetAsync(node_acc, 0, sizeof(float) * N_NODESC * DIM, stream);
    k_rel_reduce<<<NREL * RCHUNK, 128, 0, stream>>>(nfl, mask, rel_sum, cnt);
    k_rel_div<<<(NREL * DIM + 255) / 256, 256, 0, stream>>>(rel_sum, cnt, rel_emb);
    k_edge_msg<<<egrid, 256, 0, stream>>>(
        nfl, ef, rel_emb, src, dst, ety,
        W1h + (size_t)l * 128 * 384, W1l + (size_t)l * 128 * 384, b1 + l * DIM, node_acc);
    if (l == 0) {
      k_edge_gru<<<egrid, 256, 0, stream>>>(
          nfl, ef, rel_emb, src, dst, ety,
          W2h, W2l, Wihh, Wihl, Whhh, Whhl, b2, bih, bhh);
    }
    k_node<<<(N_NODESC + 63) / 64, 256, 0, stream>>>(
        nfl, node_acc, deg, W3t + (size_t)l * DIM * DIM, b3 + l * DIM, out);
  }
}